// Round 5
// baseline (106.362 us; speedup 1.0000x reference)
//
#include <hip/hip_runtime.h>

// Problem constants: B=4, L=512, D=128, C=128
#define NB 4
#define SL 512
#define DD 128
#define CC 128

__device__ __forceinline__ float fexp2(float x) { return __builtin_amdgcn_exp2f(x); }
__device__ __forceinline__ float frcp(float x)  { return __builtin_amdgcn_rcpf(x); }

// Kernel 1: projections. 2 rows/block, 1024 blocks.
//   p2 [B*L, C]   = 2*log2(e) * (inps @ wei_t + bxh)
//   k2T [B, C, L] = 2*log2(e) * (inps @ wei_x)^T
__global__ __launch_bounds__(256) void proj_kernel(
    const float* __restrict__ inps, const float* __restrict__ wei_t,
    const float* __restrict__ wei_x, const float* __restrict__ bxh,
    float* __restrict__ p2, float* __restrict__ k2T)
{
    const float K2 = 2.8853900817779268f;  // 2*log2(e)
    const int row0 = blockIdx.x * 2;       // global row = b*SL + i
    const int b    = row0 >> 9;
    const int i0   = row0 & 511;
    const int c    = threadIdx.x & 127;
    const int sel  = threadIdx.x >> 7;     // wave-uniform: waves 0-1 wei_t, 2-3 wei_x

    const float* W  = sel ? wei_x : wei_t;
    const float* r0 = inps + (size_t)row0 * DD;   // uniform -> s_load
    const float* r1 = r0 + DD;

    float a0 = 0.f, a1 = 0.f;
    #pragma unroll 8
    for (int k = 0; k < DD; ++k) {
        float w = W[k * CC + c];           // coalesced across c
        a0 = fmaf(r0[k], w, a0);
        a1 = fmaf(r1[k], w, a1);
    }

    if (sel == 0) {
        float bb = bxh[c];
        p2[(size_t)(row0 + 0) * CC + c] = K2 * (a0 + bb);
        p2[(size_t)(row0 + 1) * CC + c] = K2 * (a1 + bb);
    } else {
        float2 v = {K2 * a0, K2 * a1};
        *reinterpret_cast<float2*>(&k2T[((size_t)b * CC + c) * SL + i0]) = v;
    }
}

// Kernel 2: one block per (b, 2 rows of i). 512 threads, thread = j.
// 1024 blocks = 4 blocks/CU = 32 waves/CU.
// Phase-B uniforms come from ONE broadcast ds_read_b128 per c (no SMEM
// streaming in the hot loop — rounds 3/4 stalled all waves on s_load latency).
// Softmax max-pass dropped: scores bounded (|s| <= 2*sum|wa| ~ 18), and since
// sum_j e^{s_j - max} >= 1 the eps-difference vs reference is <= 1e-7 relative.
__global__ __launch_bounds__(512, 8) void attn_kernel(
    const float* __restrict__ inps, const float* __restrict__ wei_a,
    const float* __restrict__ p2, const float* __restrict__ k2T,
    float* __restrict__ out)
{
    __shared__ float4 upk[CC];             // {p2[i0,c], p2[i0+1,c], wa[c], 0} -> broadcast b128
    __shared__ float scT[SL * 2];          // a[i][j] stored [j][2]
    __shared__ float reds[2 * 8];
    __shared__ float redbuf[2 * 16 * DD];  // 16 KB phase-D partials

    const int blk = blockIdx.x;            // 1024 blocks
    const int b   = blk >> 8;
    const int i0  = (blk & 255) * 2;
    const int bi0 = b * SL + i0;
    const int tid = threadIdx.x;
    const int j   = tid;                   // 0..511
    const int lane = tid & 63, wv = tid >> 6;

    // Phase A: stage block-uniform data in LDS (coalesced loads by 128 threads)
    if (tid < CC) {
        float4 u;
        u.x = p2[(size_t)(bi0 + 0) * CC + tid];
        u.y = p2[(size_t)(bi0 + 1) * CC + tid];
        u.z = wei_a[tid];
        u.w = 0.f;
        upk[tid] = u;
    }
    __syncthreads();

    // Phase B: s_acc[i] = sum_c wa[c] / (exp2(p2[i,c] + k2T[c,j]) + 1)
    const float* kb = k2T + (size_t)b * CC * SL + j;
    float s0 = 0.f, s1 = 0.f;
    #pragma unroll 8
    for (int c = 0; c < CC; ++c) {
        float kv = kb[(size_t)c * SL];     // coalesced 4B/lane, L2-resident
        float4 u = upk[c];                 // broadcast ds_read_b128 (~free)
        s0 = fmaf(u.z, frcp(fexp2(u.x + kv) + 1.0f), s0);
        s1 = fmaf(u.z, frcp(fexp2(u.y + kv) + 1.0f), s1);
    }

    // Phase C: e = exp(score') = exp2(KE * s_acc), KE = -2*log2(e)
    // (true score = const - 2*s_acc; const dropped — softmax shift-invariant)
    const float KE = -2.8853900817779268f;
    float e0 = fexp2(s0 * KE);
    float e1 = fexp2(s1 * KE);
    float ss0 = e0, ss1 = e1;
    #pragma unroll
    for (int off = 32; off > 0; off >>= 1) {
        ss0 += __shfl_xor(ss0, off, 64);
        ss1 += __shfl_xor(ss1, off, 64);
    }
    if (lane == 0) { reds[wv] = ss0; reds[8 + wv] = ss1; }
    __syncthreads();
    {
        float S0 = reds[0] + reds[1] + reds[2] + reds[3] + reds[4] + reds[5] + reds[6] + reds[7];
        float S1 = reds[8] + reds[9] + reds[10] + reds[11] + reds[12] + reds[13] + reds[14] + reds[15];
        float2 av = {e0 * frcp(S0 + 1e-7f), e1 * frcp(S1 + 1e-7f)};
        *reinterpret_cast<float2*>(&scT[j * 2]) = av;   // a[i][j], [j][2] layout
    }
    __syncthreads();

    // Phase D: out[i0+i, :] = sum_j a[i][j] * inps[b, j, :], 2 rows at once.
    const int dq = (tid & 31) * 4;
    const int jq = tid >> 5;
    const float* ibase = inps + (size_t)b * SL * DD;
    float4 acc0 = {0,0,0,0}, acc1 = {0,0,0,0};
    const int jb = jq * 32;
    #pragma unroll 4
    for (int jj = 0; jj < 32; ++jj) {
        int jx = jb + jj;
        float4 v  = *reinterpret_cast<const float4*>(ibase + (size_t)jx * DD + dq);
        float2 a2 = *reinterpret_cast<const float2*>(&scT[jx * 2]);  // broadcast
        acc0.x = fmaf(a2.x, v.x, acc0.x); acc0.y = fmaf(a2.x, v.y, acc0.y);
        acc0.z = fmaf(a2.x, v.z, acc0.z); acc0.w = fmaf(a2.x, v.w, acc0.w);
        acc1.x = fmaf(a2.y, v.x, acc1.x); acc1.y = fmaf(a2.y, v.y, acc1.y);
        acc1.z = fmaf(a2.y, v.z, acc1.z); acc1.w = fmaf(a2.y, v.w, acc1.w);
    }
    *reinterpret_cast<float4*>(&redbuf[(0 * 16 + jq) * DD + dq]) = acc0;
    *reinterpret_cast<float4*>(&redbuf[(1 * 16 + jq) * DD + dq]) = acc1;
    __syncthreads();
    if (tid < 2 * DD) {
        int i = tid >> 7, d = tid & 127;
        float sum = 0.f;
        #pragma unroll
        for (int q = 0; q < 16; ++q) sum += redbuf[(i * 16 + q) * DD + d];
        out[(size_t)(bi0 + i) * DD + d] = sum;
    }
}

extern "C" void kernel_launch(void* const* d_in, const int* in_sizes, int n_in,
                              void* d_out, int out_size, void* d_ws, size_t ws_size,
                              hipStream_t stream) {
    const float* inps  = (const float*)d_in[0];  // [B, L, D]
    const float* wei_t = (const float*)d_in[1];  // [D, C]
    const float* wei_x = (const float*)d_in[2];  // [D, C]
    const float* bxh   = (const float*)d_in[3];  // [C]
    const float* wei_a = (const float*)d_in[4];  // [C]
    // d_in[5] = bxa (scalar): uniform shift before softmax -> dropped.
    float* out = (float*)d_out;                  // [B, L, D] fp32

    float* p2  = (float*)d_ws;                   // [B*L, C]   1 MB
    float* k2T = p2 + (size_t)NB * SL * CC;      // [B, C, L]  1 MB

    proj_kernel<<<NB * SL / 2, 256, 0, stream>>>(inps, wei_t, wei_x, bxh, p2, k2T);
    attn_kernel<<<NB * SL / 2, 512, 0, stream>>>(inps, wei_a, p2, k2T, out);
}

// Round 6
// 98.524 us; speedup vs baseline: 1.0796x; 1.0796x over previous
//
#include <hip/hip_runtime.h>

// Problem constants: B=4, L=512, D=128, C=128
#define NB 4
#define SL 512
#define DD 128
#define CC 128

__device__ __forceinline__ float fexp2(float x) { return __builtin_amdgcn_exp2f(x); }
__device__ __forceinline__ float frcp(float x)  { return __builtin_amdgcn_rcpf(x); }

// Kernel 1: projections, EXPONENTIATED (trans factorization):
//   E  [B*L, C]  = exp2( K2 * (inps @ wei_t + bxh) )
//   F  [B, C, L] = exp2( K2 * (inps @ wei_x) )^T
// so that exp2(K2*(qt_ic + kx_jc + b_c)) = E_ic * F_jc — this moves one of the
// two trans ops per (i,j,c) element out of the O(L^2 C) loop into O(L C).
__global__ __launch_bounds__(256) void proj_kernel(
    const float* __restrict__ inps, const float* __restrict__ wei_t,
    const float* __restrict__ wei_x, const float* __restrict__ bxh,
    float* __restrict__ E, float* __restrict__ F)
{
    const float K2 = 2.8853900817779268f;  // 2*log2(e)
    const int row0 = blockIdx.x * 2;       // global row = b*SL + i
    const int b    = row0 >> 9;
    const int i0   = row0 & 511;
    const int c    = threadIdx.x & 127;
    const int sel  = threadIdx.x >> 7;     // wave-uniform: waves 0-1 wei_t, 2-3 wei_x

    const float* W  = sel ? wei_x : wei_t;
    const float* r0 = inps + (size_t)row0 * DD;   // uniform -> s_load
    const float* r1 = r0 + DD;

    float a0 = 0.f, a1 = 0.f;
    #pragma unroll 8
    for (int k = 0; k < DD; ++k) {
        float w = W[k * CC + c];           // coalesced across c
        a0 = fmaf(r0[k], w, a0);
        a1 = fmaf(r1[k], w, a1);
    }

    if (sel == 0) {
        float bb = bxh[c];
        E[(size_t)(row0 + 0) * CC + c] = fexp2(K2 * (a0 + bb));
        E[(size_t)(row0 + 1) * CC + c] = fexp2(K2 * (a1 + bb));
    } else {
        float2 v = {fexp2(K2 * a0), fexp2(K2 * a1)};
        *reinterpret_cast<float2*>(&F[((size_t)b * CC + c) * SL + i0]) = v;
    }
}

// Kernel 2: one block per (b, 2 rows of i). 512 threads, thread = j.
// 1024 blocks = 4 blocks/CU = 32 waves/CU.
// Inner loop per element:  wa_c / (E_ic*F_jc + 1)  = v_fma + v_rcp + v_fmac
//   -> 1 trans + 2 VALU per element (was 2 trans + 3 VALU).
// E pairs come from one broadcast ds_read_b64; wa is grid-constant -> s_load
// (K$-resident, 512 B). Softmax max-pass dropped (scores bounded, sum >= 1
// so the +eps behavior matches reference to <= 1e-7 relative).
__global__ __launch_bounds__(512, 8) void attn_kernel(
    const float* __restrict__ inps, const float* __restrict__ wei_a,
    const float* __restrict__ E, const float* __restrict__ F,
    float* __restrict__ out)
{
    __shared__ float2 upk[CC];             // {E[i0,c], E[i0+1,c]} -> broadcast b64
    __shared__ float scT[SL * 2];          // a[i][j] stored [j][2]
    __shared__ float reds[2 * 8];
    __shared__ float redbuf[2 * 16 * DD];  // 16 KB phase-D partials

    const int blk = blockIdx.x;            // 1024 blocks
    const int b   = blk >> 8;
    const int i0  = (blk & 255) * 2;
    const int bi0 = b * SL + i0;
    const int tid = threadIdx.x;
    const int j   = tid;                   // 0..511
    const int lane = tid & 63, wv = tid >> 6;

    // Phase A: stage the two block-uniform E rows as pairs (coalesced)
    if (tid < CC) {
        float2 u;
        u.x = E[(size_t)(bi0 + 0) * CC + tid];
        u.y = E[(size_t)(bi0 + 1) * CC + tid];
        upk[tid] = u;
    }
    __syncthreads();

    // Phase B: s_acc[i] = sum_c wa[c] / (E[i,c]*F[c,j] + 1)
    const float* fb = F + (size_t)b * CC * SL + j;
    float s0 = 0.f, s1 = 0.f;
    #pragma unroll 8
    for (int c = 0; c < CC; ++c) {
        float fv = fb[(size_t)c * SL];     // coalesced 4B/lane, L2-resident
        float2 u = upk[c];                 // broadcast ds_read_b64
        float wc = wei_a[c];               // grid-constant -> s_load (K$ hot)
        s0 = fmaf(wc, frcp(fmaf(u.x, fv, 1.0f)), s0);
        s1 = fmaf(wc, frcp(fmaf(u.y, fv, 1.0f)), s1);
    }

    // Phase C: e = exp(score') = exp2(KE * s_acc), KE = -2*log2(e)
    // (true score = const - 2*s_acc; const dropped — softmax shift-invariant)
    const float KE = -2.8853900817779268f;
    float e0 = fexp2(s0 * KE);
    float e1 = fexp2(s1 * KE);
    float ss0 = e0, ss1 = e1;
    #pragma unroll
    for (int off = 32; off > 0; off >>= 1) {
        ss0 += __shfl_xor(ss0, off, 64);
        ss1 += __shfl_xor(ss1, off, 64);
    }
    if (lane == 0) { reds[wv] = ss0; reds[8 + wv] = ss1; }
    __syncthreads();
    {
        float S0 = reds[0] + reds[1] + reds[2] + reds[3] + reds[4] + reds[5] + reds[6] + reds[7];
        float S1 = reds[8] + reds[9] + reds[10] + reds[11] + reds[12] + reds[13] + reds[14] + reds[15];
        float2 av = {e0 * frcp(S0 + 1e-7f), e1 * frcp(S1 + 1e-7f)};
        *reinterpret_cast<float2*>(&scT[j * 2]) = av;   // a[i][j], [j][2] layout
    }
    __syncthreads();

    // Phase D: out[i0+i, :] = sum_j a[i][j] * inps[b, j, :], 2 rows at once.
    const int dq = (tid & 31) * 4;
    const int jq = tid >> 5;
    const float* ibase = inps + (size_t)b * SL * DD;
    float4 acc0 = {0,0,0,0}, acc1 = {0,0,0,0};
    const int jb = jq * 32;
    #pragma unroll 4
    for (int jj = 0; jj < 32; ++jj) {
        int jx = jb + jj;
        float4 v  = *reinterpret_cast<const float4*>(ibase + (size_t)jx * DD + dq);
        float2 a2 = *reinterpret_cast<const float2*>(&scT[jx * 2]);  // broadcast
        acc0.x = fmaf(a2.x, v.x, acc0.x); acc0.y = fmaf(a2.x, v.y, acc0.y);
        acc0.z = fmaf(a2.x, v.z, acc0.z); acc0.w = fmaf(a2.x, v.w, acc0.w);
        acc1.x = fmaf(a2.y, v.x, acc1.x); acc1.y = fmaf(a2.y, v.y, acc1.y);
        acc1.z = fmaf(a2.y, v.z, acc1.z); acc1.w = fmaf(a2.y, v.w, acc1.w);
    }
    *reinterpret_cast<float4*>(&redbuf[(0 * 16 + jq) * DD + dq]) = acc0;
    *reinterpret_cast<float4*>(&redbuf[(1 * 16 + jq) * DD + dq]) = acc1;
    __syncthreads();
    if (tid < 2 * DD) {
        int i = tid >> 7, d = tid & 127;
        float sum = 0.f;
        #pragma unroll
        for (int q = 0; q < 16; ++q) sum += redbuf[(i * 16 + q) * DD + d];
        out[(size_t)(bi0 + i) * DD + d] = sum;
    }
}

extern "C" void kernel_launch(void* const* d_in, const int* in_sizes, int n_in,
                              void* d_out, int out_size, void* d_ws, size_t ws_size,
                              hipStream_t stream) {
    const float* inps  = (const float*)d_in[0];  // [B, L, D]
    const float* wei_t = (const float*)d_in[1];  // [D, C]
    const float* wei_x = (const float*)d_in[2];  // [D, C]
    const float* bxh   = (const float*)d_in[3];  // [C]
    const float* wei_a = (const float*)d_in[4];  // [C]
    // d_in[5] = bxa (scalar): uniform shift before softmax -> dropped.
    float* out = (float*)d_out;                  // [B, L, D] fp32

    float* E = (float*)d_ws;                     // [B*L, C]   1 MB
    float* F = E + (size_t)NB * SL * CC;         // [B, C, L]  1 MB

    proj_kernel<<<NB * SL / 2, 256, 0, stream>>>(inps, wei_t, wei_x, bxh, E, F);
    attn_kernel<<<NB * SL / 2, 512, 0, stream>>>(inps, wei_a, E, F, out);
}

// Round 7
// 97.554 us; speedup vs baseline: 1.0903x; 1.0099x over previous
//
#include <hip/hip_runtime.h>

// Problem constants: B=4, L=512, D=128, C=128
#define NB 4
#define SL 512
#define DD 128
#define CC 128

__device__ __forceinline__ float fexp2(float x) { return __builtin_amdgcn_exp2f(x); }
__device__ __forceinline__ float frcp(float x)  { return __builtin_amdgcn_rcpf(x); }

// Kernel 1: projections, EXPONENTIATED (trans factorization):
//   E  [B*L, C]  = exp2( K2 * (inps @ wei_t + bxh) )
//   F  [B, C, L] = exp2( K2 * (inps @ wei_x) )^T
// so that exp2(K2*(qt_ic + kx_jc + b_c)) = E_ic * F_jc — one trans op per
// O(L^2 C) element instead of two.
__global__ __launch_bounds__(256) void proj_kernel(
    const float* __restrict__ inps, const float* __restrict__ wei_t,
    const float* __restrict__ wei_x, const float* __restrict__ bxh,
    float* __restrict__ E, float* __restrict__ F)
{
    const float K2 = 2.8853900817779268f;  // 2*log2(e)
    const int row0 = blockIdx.x * 2;       // global row = b*SL + i
    const int b    = row0 >> 9;
    const int i0   = row0 & 511;
    const int c    = threadIdx.x & 127;
    const int sel  = threadIdx.x >> 7;     // wave-uniform: waves 0-1 wei_t, 2-3 wei_x

    const float* W  = sel ? wei_x : wei_t;
    const float* r0 = inps + (size_t)row0 * DD;   // uniform -> s_load
    const float* r1 = r0 + DD;

    float a0 = 0.f, a1 = 0.f;
    #pragma unroll 8
    for (int k = 0; k < DD; ++k) {
        float w = W[k * CC + c];           // coalesced across c
        a0 = fmaf(r0[k], w, a0);
        a1 = fmaf(r1[k], w, a1);
    }

    if (sel == 0) {
        float bb = bxh[c];
        E[(size_t)(row0 + 0) * CC + c] = fexp2(K2 * (a0 + bb));
        E[(size_t)(row0 + 1) * CC + c] = fexp2(K2 * (a1 + bb));
    } else {
        float2 v = {fexp2(K2 * a0), fexp2(K2 * a1)};
        *reinterpret_cast<float2*>(&F[((size_t)b * CC + c) * SL + i0]) = v;
    }
}

// Kernel 2: one block per (b, 2 rows of i). 256 threads, thread = 2 j's.
// 1024 blocks = 4 blocks/CU = 16 waves/CU.
// Inner c-iter: 1 ds_read_b64 (E pair) + 1 float2 F-load + 4 fma/4 rcp/4 fmac
// for FOUR elements — halves per-element LDS-pipe cost vs round 6 (the
// round-6 pipe audit put LDS at 10.2 us/CU, the largest reducible term).
// Softmax max-pass dropped (scores bounded, sum >= 1 so +eps matches
// reference to <= 1e-7 relative).
__global__ __launch_bounds__(256, 4) void attn_kernel(
    const float* __restrict__ inps, const float* __restrict__ wei_a,
    const float* __restrict__ E, const float* __restrict__ F,
    float* __restrict__ out)
{
    __shared__ float2 upk[CC];             // {E[i0,c], E[i0+1,c]} -> broadcast b64
    __shared__ float scT[SL * 2];          // a[i][j] stored [j][2]
    __shared__ float reds[2 * 4];
    __shared__ float redbuf[2 * 8 * DD];   // 8 KB phase-D partials

    const int blk = blockIdx.x;            // 1024 blocks
    const int b   = blk >> 8;
    const int i0  = (blk & 255) * 2;
    const int bi0 = b * SL + i0;
    const int tid = threadIdx.x;
    const int j0  = tid * 2;               // this thread's j pair
    const int lane = tid & 63, wv = tid >> 6;   // 4 waves

    // Phase A: stage the two block-uniform E rows as pairs (coalesced)
    if (tid < CC) {
        float2 u;
        u.x = E[(size_t)(bi0 + 0) * CC + tid];
        u.y = E[(size_t)(bi0 + 1) * CC + tid];
        upk[tid] = u;
    }
    __syncthreads();

    // Phase B: s[i][j] = sum_c wa[c] / (E[i,c]*F[c,j] + 1), i in {0,1}, j in {j0,j0+1}
    const float* fb = F + (size_t)b * CC * SL + j0;
    float s00 = 0.f, s01 = 0.f, s10 = 0.f, s11 = 0.f;
    #pragma unroll 8
    for (int c = 0; c < CC; ++c) {
        float2 fv = *reinterpret_cast<const float2*>(&fb[(size_t)c * SL]); // 8B/lane coalesced
        float2 u  = upk[c];                // broadcast ds_read_b64
        float wc  = wei_a[c];              // grid-constant -> s_load (K$ hot)
        s00 = fmaf(wc, frcp(fmaf(u.x, fv.x, 1.0f)), s00);
        s01 = fmaf(wc, frcp(fmaf(u.x, fv.y, 1.0f)), s01);
        s10 = fmaf(wc, frcp(fmaf(u.y, fv.x, 1.0f)), s10);
        s11 = fmaf(wc, frcp(fmaf(u.y, fv.y, 1.0f)), s11);
    }

    // Phase C: e = exp2(KE * s), KE = -2*log2(e); row sums over 4 waves.
    const float KE = -2.8853900817779268f;
    float e00 = fexp2(s00 * KE), e01 = fexp2(s01 * KE);
    float e10 = fexp2(s10 * KE), e11 = fexp2(s11 * KE);
    float ss0 = e00 + e01, ss1 = e10 + e11;
    #pragma unroll
    for (int off = 32; off > 0; off >>= 1) {
        ss0 += __shfl_xor(ss0, off, 64);
        ss1 += __shfl_xor(ss1, off, 64);
    }
    if (lane == 0) { reds[wv] = ss0; reds[4 + wv] = ss1; }
    __syncthreads();
    {
        float S0 = reds[0] + reds[1] + reds[2] + reds[3];
        float S1 = reds[4] + reds[5] + reds[6] + reds[7];
        float r0 = frcp(S0 + 1e-7f), r1 = frcp(S1 + 1e-7f);
        // a[i][j] at scT[j*2+i]; this thread's two j's are contiguous -> float4
        float4 av = {e00 * r0, e10 * r1, e01 * r0, e11 * r1};
        *reinterpret_cast<float4*>(&scT[j0 * 2]) = av;
    }
    __syncthreads();

    // Phase D: out[i0+i, :] = sum_j a[i][j] * inps[b, j, :], 2 rows at once.
    // dq = float4 of d (32 quads), jq = tid>>5 -> 8-way j split (64 j each).
    const int dq = (tid & 31) * 4;
    const int jq = tid >> 5;
    const float* ibase = inps + (size_t)b * SL * DD;
    float4 acc0 = {0,0,0,0}, acc1 = {0,0,0,0};
    const int jb = jq * 64;
    #pragma unroll 4
    for (int jj = 0; jj < 64; ++jj) {
        int jx = jb + jj;
        float4 v  = *reinterpret_cast<const float4*>(ibase + (size_t)jx * DD + dq);
        float2 a2 = *reinterpret_cast<const float2*>(&scT[jx * 2]);  // broadcast
        acc0.x = fmaf(a2.x, v.x, acc0.x); acc0.y = fmaf(a2.x, v.y, acc0.y);
        acc0.z = fmaf(a2.x, v.z, acc0.z); acc0.w = fmaf(a2.x, v.w, acc0.w);
        acc1.x = fmaf(a2.y, v.x, acc1.x); acc1.y = fmaf(a2.y, v.y, acc1.y);
        acc1.z = fmaf(a2.y, v.z, acc1.z); acc1.w = fmaf(a2.y, v.w, acc1.w);
    }
    *reinterpret_cast<float4*>(&redbuf[(0 * 8 + jq) * DD + dq]) = acc0;
    *reinterpret_cast<float4*>(&redbuf[(1 * 8 + jq) * DD + dq]) = acc1;
    __syncthreads();
    {
        int i = tid >> 7, d = tid & 127;   // 256 threads = 2 rows x 128 d
        float sum = 0.f;
        #pragma unroll
        for (int q = 0; q < 8; ++q) sum += redbuf[(i * 8 + q) * DD + d];
        out[(size_t)(bi0 + i) * DD + d] = sum;
    }
}

extern "C" void kernel_launch(void* const* d_in, const int* in_sizes, int n_in,
                              void* d_out, int out_size, void* d_ws, size_t ws_size,
                              hipStream_t stream) {
    const float* inps  = (const float*)d_in[0];  // [B, L, D]
    const float* wei_t = (const float*)d_in[1];  // [D, C]
    const float* wei_x = (const float*)d_in[2];  // [D, C]
    const float* bxh   = (const float*)d_in[3];  // [C]
    const float* wei_a = (const float*)d_in[4];  // [C]
    // d_in[5] = bxa (scalar): uniform shift before softmax -> dropped.
    float* out = (float*)d_out;                  // [B, L, D] fp32

    float* E = (float*)d_ws;                     // [B*L, C]   1 MB
    float* F = E + (size_t)NB * SL * CC;         // [B, C, L]  1 MB

    proj_kernel<<<NB * SL / 2, 256, 0, stream>>>(inps, wei_t, wei_x, bxh, E, F);
    attn_kernel<<<NB * SL / 2, 256, 0, stream>>>(inps, wei_a, E, F, out);
}

// Round 8
// 95.434 us; speedup vs baseline: 1.1145x; 1.0222x over previous
//
#include <hip/hip_runtime.h>

// Problem constants: B=4, L=512, D=128, C=128
#define NB 4
#define SL 512
#define DD 128
#define CC 128

__device__ __forceinline__ float fexp2(float x) { return __builtin_amdgcn_exp2f(x); }
__device__ __forceinline__ float frcp(float x)  { return __builtin_amdgcn_rcpf(x); }

// Kernel 1: projections, EXPONENTIATED (trans factorization):
//   E  [B*L, C]  = exp2( K2 * (inps @ wei_t + bxh) )
//   F  [B, C, L] = exp2( K2 * (inps @ wei_x) )^T
// so that exp2(K2*(qt_ic + kx_jc + b_c)) = E_ic * F_jc — one trans op per
// O(L^2 C) element instead of two.
__global__ __launch_bounds__(256) void proj_kernel(
    const float* __restrict__ inps, const float* __restrict__ wei_t,
    const float* __restrict__ wei_x, const float* __restrict__ bxh,
    float* __restrict__ E, float* __restrict__ F)
{
    const float K2 = 2.8853900817779268f;  // 2*log2(e)
    const int row0 = blockIdx.x * 2;       // global row = b*SL + i
    const int b    = row0 >> 9;
    const int i0   = row0 & 511;
    const int c    = threadIdx.x & 127;
    const int sel  = threadIdx.x >> 7;     // wave-uniform: waves 0-1 wei_t, 2-3 wei_x

    const float* W  = sel ? wei_x : wei_t;
    const float* r0 = inps + (size_t)row0 * DD;   // uniform -> s_load
    const float* r1 = r0 + DD;

    float a0 = 0.f, a1 = 0.f;
    #pragma unroll 8
    for (int k = 0; k < DD; ++k) {
        float w = W[k * CC + c];           // coalesced across c
        a0 = fmaf(r0[k], w, a0);
        a1 = fmaf(r1[k], w, a1);
    }

    if (sel == 0) {
        float bb = bxh[c];
        E[(size_t)(row0 + 0) * CC + c] = fexp2(K2 * (a0 + bb));
        E[(size_t)(row0 + 1) * CC + c] = fexp2(K2 * (a1 + bb));
    } else {
        float2 v = {fexp2(K2 * a0), fexp2(K2 * a1)};
        *reinterpret_cast<float2*>(&F[((size_t)b * CC + c) * SL + i0]) = v;
    }
}

// Kernel 2: one block per (b, 4 rows of i). 512 blocks x 512 threads, thread=j.
// i-tile=4 attacks the L1-BW wall found in the round-7 audit: phase D's inps
// stream drops from 1 MB/CU (i-tile 2) to 512 KB per 2 resident blocks (each
// float4 feeds 4 rows), and each phase-B F-load/E-ds_read feeds 4 elements.
// Softmax max-pass dropped (scores bounded |s|<=2*sum|wa|~18, sum>=1 so +eps
// matches reference to <=1e-7 relative).
__global__ __launch_bounds__(512, 4) void attn_kernel(
    const float* __restrict__ inps, const float* __restrict__ wei_a,
    const float* __restrict__ E, const float* __restrict__ F,
    float* __restrict__ out)
{
    __shared__ float4 upk[CC];             // {E[i0..i0+3, c]} -> broadcast b128
    __shared__ float scT[SL * 4];          // a[i][j] stored [j][4]
    __shared__ float redw[4 * 8];
    __shared__ float redbuf[4 * 16 * DD];  // 32 KB phase-D partials

    const int blk = blockIdx.x;            // 512 blocks
    const int b   = blk >> 7;
    const int i0  = (blk & 127) * 4;
    const int bi0 = b * SL + i0;
    const int tid = threadIdx.x;
    const int j   = tid;                   // 0..511
    const int lane = tid & 63, wv = tid >> 6;   // 8 waves

    // Phase A: stage the four block-uniform E rows as quads (by 128 threads)
    if (tid < CC) {
        float4 u;
        u.x = E[(size_t)(bi0 + 0) * CC + tid];
        u.y = E[(size_t)(bi0 + 1) * CC + tid];
        u.z = E[(size_t)(bi0 + 2) * CC + tid];
        u.w = E[(size_t)(bi0 + 3) * CC + tid];
        upk[tid] = u;
    }
    __syncthreads();

    // Phase B: s[i] = sum_c wa[c] / (E[i,c]*F[c,j] + 1), i in 0..3.
    // Per c-iter: 1x 4B F-load (coalesced, L2) + 1 broadcast ds_read_b128 +
    // 4 fma + 4 rcp + 4 fmac -> 4 elements. Unroll 8 => 8 indep loads in flight.
    const float* fb = F + (size_t)b * CC * SL + j;
    float s0 = 0.f, s1 = 0.f, s2 = 0.f, s3 = 0.f;
    #pragma unroll 8
    for (int c = 0; c < CC; ++c) {
        float fv = fb[(size_t)c * SL];
        float4 u = upk[c];                 // broadcast ds_read_b128
        float wc = wei_a[c];               // grid-constant -> s_load (K$ hot)
        s0 = fmaf(wc, frcp(fmaf(u.x, fv, 1.0f)), s0);
        s1 = fmaf(wc, frcp(fmaf(u.y, fv, 1.0f)), s1);
        s2 = fmaf(wc, frcp(fmaf(u.z, fv, 1.0f)), s2);
        s3 = fmaf(wc, frcp(fmaf(u.w, fv, 1.0f)), s3);
    }

    // Phase C: e = exp2(KE * s), KE = -2*log2(e); row sums over 8 waves.
    const float KE = -2.8853900817779268f;
    float e0 = fexp2(s0 * KE), e1 = fexp2(s1 * KE);
    float e2 = fexp2(s2 * KE), e3 = fexp2(s3 * KE);
    float t0 = e0, t1 = e1, t2 = e2, t3 = e3;
    #pragma unroll
    for (int off = 32; off > 0; off >>= 1) {
        t0 += __shfl_xor(t0, off, 64);
        t1 += __shfl_xor(t1, off, 64);
        t2 += __shfl_xor(t2, off, 64);
        t3 += __shfl_xor(t3, off, 64);
    }
    if (lane == 0) {
        redw[0 * 8 + wv] = t0; redw[1 * 8 + wv] = t1;
        redw[2 * 8 + wv] = t2; redw[3 * 8 + wv] = t3;
    }
    __syncthreads();
    {
        float S0 = 0.f, S1 = 0.f, S2 = 0.f, S3 = 0.f;
        #pragma unroll
        for (int q = 0; q < 8; ++q) {
            S0 += redw[0 * 8 + q]; S1 += redw[1 * 8 + q];
            S2 += redw[2 * 8 + q]; S3 += redw[3 * 8 + q];
        }
        float4 av = {e0 * frcp(S0 + 1e-7f), e1 * frcp(S1 + 1e-7f),
                     e2 * frcp(S2 + 1e-7f), e3 * frcp(S3 + 1e-7f)};
        *reinterpret_cast<float4*>(&scT[j * 4]) = av;   // a[i][j], [j][4] layout
    }
    __syncthreads();

    // Phase D: out[i0+i, :] = sum_j a[i][j] * inps[b, j, :], 4 rows at once.
    // dq = float4 of d (32 quads), jq = tid>>5 -> 16-way j split (32 j each).
    // Each inps float4 is loaded ONCE per block and feeds 4 output rows.
    const int dq = (tid & 31) * 4;
    const int jq = tid >> 5;
    const float* ibase = inps + (size_t)b * SL * DD;
    float4 acc0 = {0,0,0,0}, acc1 = {0,0,0,0}, acc2 = {0,0,0,0}, acc3 = {0,0,0,0};
    const int jb = jq * 32;
    #pragma unroll 4
    for (int jj = 0; jj < 32; ++jj) {
        int jx = jb + jj;
        float4 v  = *reinterpret_cast<const float4*>(ibase + (size_t)jx * DD + dq);
        float4 a4 = *reinterpret_cast<const float4*>(&scT[jx * 4]);  // broadcast
        acc0.x = fmaf(a4.x, v.x, acc0.x); acc0.y = fmaf(a4.x, v.y, acc0.y);
        acc0.z = fmaf(a4.x, v.z, acc0.z); acc0.w = fmaf(a4.x, v.w, acc0.w);
        acc1.x = fmaf(a4.y, v.x, acc1.x); acc1.y = fmaf(a4.y, v.y, acc1.y);
        acc1.z = fmaf(a4.y, v.z, acc1.z); acc1.w = fmaf(a4.y, v.w, acc1.w);
        acc2.x = fmaf(a4.z, v.x, acc2.x); acc2.y = fmaf(a4.z, v.y, acc2.y);
        acc2.z = fmaf(a4.z, v.z, acc2.z); acc2.w = fmaf(a4.z, v.w, acc2.w);
        acc3.x = fmaf(a4.w, v.x, acc3.x); acc3.y = fmaf(a4.w, v.y, acc3.y);
        acc3.z = fmaf(a4.w, v.z, acc3.z); acc3.w = fmaf(a4.w, v.w, acc3.w);
    }
    *reinterpret_cast<float4*>(&redbuf[(0 * 16 + jq) * DD + dq]) = acc0;
    *reinterpret_cast<float4*>(&redbuf[(1 * 16 + jq) * DD + dq]) = acc1;
    *reinterpret_cast<float4*>(&redbuf[(2 * 16 + jq) * DD + dq]) = acc2;
    *reinterpret_cast<float4*>(&redbuf[(3 * 16 + jq) * DD + dq]) = acc3;
    __syncthreads();
    {
        int i = tid >> 7, d = tid & 127;   // 512 threads = 4 rows x 128 d
        float sum = 0.f;
        #pragma unroll
        for (int q = 0; q < 16; ++q) sum += redbuf[(i * 16 + q) * DD + d];
        out[(size_t)(bi0 + i) * DD + d] = sum;
    }
}

extern "C" void kernel_launch(void* const* d_in, const int* in_sizes, int n_in,
                              void* d_out, int out_size, void* d_ws, size_t ws_size,
                              hipStream_t stream) {
    const float* inps  = (const float*)d_in[0];  // [B, L, D]
    const float* wei_t = (const float*)d_in[1];  // [D, C]
    const float* wei_x = (const float*)d_in[2];  // [D, C]
    const float* bxh   = (const float*)d_in[3];  // [C]
    const float* wei_a = (const float*)d_in[4];  // [C]
    // d_in[5] = bxa (scalar): uniform shift before softmax -> dropped.
    float* out = (float*)d_out;                  // [B, L, D] fp32

    float* E = (float*)d_ws;                     // [B*L, C]   1 MB
    float* F = E + (size_t)NB * SL * CC;         // [B, C, L]  1 MB

    proj_kernel<<<NB * SL / 2, 256, 0, stream>>>(inps, wei_t, wei_x, bxh, E, F);
    attn_kernel<<<NB * SL / 4, 512, 0, stream>>>(inps, wei_a, E, F, out);
}

// Round 9
// 91.011 us; speedup vs baseline: 1.1687x; 1.0486x over previous
//
#include <hip/hip_runtime.h>

// Problem constants: B=4, L=512, D=128, C=128
#define NB 4
#define SL 512
#define DD 128
#define CC 128

__device__ __forceinline__ float fexp2(float x) { return __builtin_amdgcn_exp2f(x); }
__device__ __forceinline__ float frcp(float x)  { return __builtin_amdgcn_rcpf(x); }

// Kernel 1: projections, EXPONENTIATED (trans factorization):
//   E  [B*L, C]  = exp2( K2 * (inps @ wei_t + bxh) )
//   F  [B, C, L] = exp2( K2 * (inps @ wei_x) )^T
__global__ __launch_bounds__(256) void proj_kernel(
    const float* __restrict__ inps, const float* __restrict__ wei_t,
    const float* __restrict__ wei_x, const float* __restrict__ bxh,
    float* __restrict__ E, float* __restrict__ F)
{
    const float K2 = 2.8853900817779268f;  // 2*log2(e)
    const int row0 = blockIdx.x * 2;       // global row = b*SL + i
    const int b    = row0 >> 9;
    const int i0   = row0 & 511;
    const int c    = threadIdx.x & 127;
    const int sel  = threadIdx.x >> 7;     // wave-uniform: waves 0-1 wei_t, 2-3 wei_x

    const float* W  = sel ? wei_x : wei_t;
    const float* r0 = inps + (size_t)row0 * DD;   // uniform -> s_load
    const float* r1 = r0 + DD;

    float a0 = 0.f, a1 = 0.f;
    #pragma unroll 8
    for (int k = 0; k < DD; ++k) {
        float w = W[k * CC + c];           // coalesced across c
        a0 = fmaf(r0[k], w, a0);
        a1 = fmaf(r1[k], w, a1);
    }

    if (sel == 0) {
        float bb = bxh[c];
        E[(size_t)(row0 + 0) * CC + c] = fexp2(K2 * (a0 + bb));
        E[(size_t)(row0 + 1) * CC + c] = fexp2(K2 * (a1 + bb));
    } else {
        float2 v = {fexp2(K2 * a0), fexp2(K2 * a1)};
        *reinterpret_cast<float2*>(&F[((size_t)b * CC + c) * SL + i0]) = v;
    }
}

// Kernel 2: one block per (b, 4 rows of i). 512 blocks x 512 threads.
// Thread layout in phase B: jt = tid&255 handles j = 2jt, 2jt+1 (float2 F
// loads); ch = tid>>8 handles one 64-c half (c-split keeps 16 waves/CU at
// i-tile=4). Per c-PAIR the rational-pairing identity
//   wa0/u0 + wa1/u1 = (wa0*u1 + wa1*u0) / (u0*u1),   u = E*F + 1
// uses ONE v_rcp per two c-terms (serialized-SIMD model: rcp=8cyc is the
// dominant per-element cost; pairing cuts core cyc/elem 0.219 -> 0.1875).
// Overflow-safe: u <= ~2^35, den <= 2^70. Softmax max-pass dropped (scores
// bounded, sum >= 1 -> +eps matches reference to <= 1e-7 relative).
__global__ __launch_bounds__(512, 4) void attn_kernel(
    const float* __restrict__ inps, const float* __restrict__ wei_a,
    const float* __restrict__ E, const float* __restrict__ F,
    float* __restrict__ out)
{
    __shared__ float4 upk[CC];             // E quads {E[i0..i0+3, c]}  (2 KB)
    __shared__ float smrg[256 * 9];        // c-half merge, stride 9 = conflict-free (9 KB)
    __shared__ float scT[SL * 4];          // a[i][j] stored [j][4]      (8 KB)
    __shared__ float redw[4 * 4];          // 4 rows x 4 lower-half waves
    __shared__ float redbuf[4 * 16 * DD];  // phase-D partials          (32 KB)

    const int blk = blockIdx.x;            // 512 blocks
    const int b   = blk >> 7;
    const int i0  = (blk & 127) * 4;
    const int bi0 = b * SL + i0;
    const int tid = threadIdx.x;
    const int jt  = tid & 255;             // j-pair index
    const int ch  = tid >> 8;              // c-half (wave-uniform)
    const int j0  = jt * 2;

    // Phase A: stage the four block-uniform E rows as quads (128 threads)
    if (tid < CC) {
        float4 u;
        u.x = E[(size_t)(bi0 + 0) * CC + tid];
        u.y = E[(size_t)(bi0 + 1) * CC + tid];
        u.z = E[(size_t)(bi0 + 2) * CC + tid];
        u.w = E[(size_t)(bi0 + 3) * CC + tid];
        upk[tid] = u;
    }
    __syncthreads();

    // Phase B: partial s over this thread's 64-c half, 4 i's x 2 j's.
    const int c0 = ch * 64;
    const float* fb = F + ((size_t)b * CC + c0) * SL + j0;
    const float4* up = upk + c0;
    const float* wa = wei_a + c0;          // uniform -> s_load (K$ hot)
    float sx[4] = {0.f, 0.f, 0.f, 0.f};
    float sy[4] = {0.f, 0.f, 0.f, 0.f};
    #pragma unroll 4
    for (int cp = 0; cp < 32; ++cp) {
        float2 f0 = *reinterpret_cast<const float2*>(&fb[(size_t)(2 * cp) * SL]);
        float2 f1 = *reinterpret_cast<const float2*>(&fb[(size_t)(2 * cp + 1) * SL]);
        float4 u0 = up[2 * cp];            // broadcast ds_read_b128
        float4 u1 = up[2 * cp + 1];
        float wa0 = wa[2 * cp], wa1 = wa[2 * cp + 1];
        const float* u0p = reinterpret_cast<const float*>(&u0);
        const float* u1p = reinterpret_cast<const float*>(&u1);
        #pragma unroll
        for (int i = 0; i < 4; ++i) {
            float ax = fmaf(u0p[i], f0.x, 1.0f);
            float bx = fmaf(u1p[i], f1.x, 1.0f);
            float numx = fmaf(wa0, bx, wa1 * ax);
            sx[i] = fmaf(numx, frcp(ax * bx), sx[i]);
            float ay = fmaf(u0p[i], f0.y, 1.0f);
            float by = fmaf(u1p[i], f1.y, 1.0f);
            float numy = fmaf(wa0, by, wa1 * ay);
            sy[i] = fmaf(numy, frcp(ay * by), sy[i]);
        }
    }

    // Merge c-halves through LDS (stride 9: bank = (jt*9+k)%32, gcd(9,32)=1
    // -> 2-way max, free per m136).
    if (ch == 1) {
        #pragma unroll
        for (int i = 0; i < 4; ++i) {
            smrg[jt * 9 + i]     = sx[i];
            smrg[jt * 9 + 4 + i] = sy[i];
        }
    }
    __syncthreads();

    // Phase C (lower 256 threads, 4 waves): exp + row-sum + normalize.
    if (ch == 0) {
        const float KE = -2.8853900817779268f;  // -2*log2(e)
        float ex[4], ey[4];
        const int lane = tid & 63, wv = tid >> 6;   // wv in 0..3
        #pragma unroll
        for (int i = 0; i < 4; ++i) {
            float si = sx[i] + smrg[jt * 9 + i];
            float ti = sy[i] + smrg[jt * 9 + 4 + i];
            ex[i] = fexp2(si * KE);
            ey[i] = fexp2(ti * KE);
            float t = ex[i] + ey[i];
            #pragma unroll
            for (int off = 32; off > 0; off >>= 1)
                t += __shfl_xor(t, off, 64);
            if (lane == 0) redw[i * 4 + wv] = t;
        }
        __syncthreads();
        float4 av0, av1;
        {
            float S0 = redw[0] + redw[1] + redw[2] + redw[3];
            float S1 = redw[4] + redw[5] + redw[6] + redw[7];
            float S2 = redw[8] + redw[9] + redw[10] + redw[11];
            float S3 = redw[12] + redw[13] + redw[14] + redw[15];
            float r0 = frcp(S0 + 1e-7f), r1 = frcp(S1 + 1e-7f);
            float r2 = frcp(S2 + 1e-7f), r3 = frcp(S3 + 1e-7f);
            av0 = make_float4(ex[0] * r0, ex[1] * r1, ex[2] * r2, ex[3] * r3);
            av1 = make_float4(ey[0] * r0, ey[1] * r1, ey[2] * r2, ey[3] * r3);
        }
        *reinterpret_cast<float4*>(&scT[j0 * 4])     = av0;  // a[*][j0]
        *reinterpret_cast<float4*>(&scT[j0 * 4 + 4]) = av1;  // a[*][j0+1]
    } else {
        __syncthreads();                   // match lower half's barrier
    }
    __syncthreads();

    // Phase D: out[i0+i, :] = sum_j a[i][j] * inps[b, j, :], 4 rows at once.
    // 512 threads: dq = float4 of d (32 quads), jq = tid>>5 (16-way, 32 j each).
    const int dq = (tid & 31) * 4;
    const int jq = tid >> 5;
    const float* ibase = inps + (size_t)b * SL * DD;
    float4 acc0 = {0,0,0,0}, acc1 = {0,0,0,0}, acc2 = {0,0,0,0}, acc3 = {0,0,0,0};
    const int jb = jq * 32;
    #pragma unroll 4
    for (int jj = 0; jj < 32; ++jj) {
        int jx = jb + jj;
        float4 v  = *reinterpret_cast<const float4*>(ibase + (size_t)jx * DD + dq);
        float4 a4 = *reinterpret_cast<const float4*>(&scT[jx * 4]);  // broadcast
        acc0.x = fmaf(a4.x, v.x, acc0.x); acc0.y = fmaf(a4.x, v.y, acc0.y);
        acc0.z = fmaf(a4.x, v.z, acc0.z); acc0.w = fmaf(a4.x, v.w, acc0.w);
        acc1.x = fmaf(a4.y, v.x, acc1.x); acc1.y = fmaf(a4.y, v.y, acc1.y);
        acc1.z = fmaf(a4.y, v.z, acc1.z); acc1.w = fmaf(a4.y, v.w, acc1.w);
        acc2.x = fmaf(a4.z, v.x, acc2.x); acc2.y = fmaf(a4.z, v.y, acc2.y);
        acc2.z = fmaf(a4.z, v.z, acc2.z); acc2.w = fmaf(a4.z, v.w, acc2.w);
        acc3.x = fmaf(a4.w, v.x, acc3.x); acc3.y = fmaf(a4.w, v.y, acc3.y);
        acc3.z = fmaf(a4.w, v.z, acc3.z); acc3.w = fmaf(a4.w, v.w, acc3.w);
    }
    *reinterpret_cast<float4*>(&redbuf[(0 * 16 + jq) * DD + dq]) = acc0;
    *reinterpret_cast<float4*>(&redbuf[(1 * 16 + jq) * DD + dq]) = acc1;
    *reinterpret_cast<float4*>(&redbuf[(2 * 16 + jq) * DD + dq]) = acc2;
    *reinterpret_cast<float4*>(&redbuf[(3 * 16 + jq) * DD + dq]) = acc3;
    __syncthreads();
    {
        int i = tid >> 7, d = tid & 127;   // 512 threads = 4 rows x 128 d
        float sum = 0.f;
        #pragma unroll
        for (int q = 0; q < 16; ++q) sum += redbuf[(i * 16 + q) * DD + d];
        out[(size_t)(bi0 + i) * DD + d] = sum;
    }
}

extern "C" void kernel_launch(void* const* d_in, const int* in_sizes, int n_in,
                              void* d_out, int out_size, void* d_ws, size_t ws_size,
                              hipStream_t stream) {
    const float* inps  = (const float*)d_in[0];  // [B, L, D]
    const float* wei_t = (const float*)d_in[1];  // [D, C]
    const float* wei_x = (const float*)d_in[2];  // [D, C]
    const float* bxh   = (const float*)d_in[3];  // [C]
    const float* wei_a = (const float*)d_in[4];  // [C]
    // d_in[5] = bxa (scalar): uniform shift before softmax -> dropped.
    float* out = (float*)d_out;                  // [B, L, D] fp32

    float* E = (float*)d_ws;                     // [B*L, C]   1 MB
    float* F = E + (size_t)NB * SL * CC;         // [B, C, L]  1 MB

    proj_kernel<<<NB * SL / 2, 256, 0, stream>>>(inps, wei_t, wei_x, bxh, E, F);
    attn_kernel<<<NB * SL / 4, 512, 0, stream>>>(inps, wei_a, E, F, out);
}

// Round 10
// 90.214 us; speedup vs baseline: 1.1790x; 1.0088x over previous
//
#include <hip/hip_runtime.h>

// Problem constants: B=4, L=512, D=128, C=128
#define NB 4
#define SL 512
#define DD 128
#define CC 128

__device__ __forceinline__ float fexp2(float x) { return __builtin_amdgcn_exp2f(x); }
__device__ __forceinline__ float frcp(float x)  { return __builtin_amdgcn_rcpf(x); }

// Kernel 1: projections, EXPONENTIATED (trans factorization):
//   E  [B*L, C]  = exp2( K2 * (inps @ wei_t + bxh) )
//   F  [B, C, L] = exp2( K2 * (inps @ wei_x) )^T
__global__ __launch_bounds__(256) void proj_kernel(
    const float* __restrict__ inps, const float* __restrict__ wei_t,
    const float* __restrict__ wei_x, const float* __restrict__ bxh,
    float* __restrict__ E, float* __restrict__ F)
{
    const float K2 = 2.8853900817779268f;  // 2*log2(e)
    const int row0 = blockIdx.x * 2;       // global row = b*SL + i
    const int b    = row0 >> 9;
    const int i0   = row0 & 511;
    const int c    = threadIdx.x & 127;
    const int sel  = threadIdx.x >> 7;     // wave-uniform: waves 0-1 wei_t, 2-3 wei_x

    const float* W  = sel ? wei_x : wei_t;
    const float* r0 = inps + (size_t)row0 * DD;   // uniform -> s_load
    const float* r1 = r0 + DD;

    float a0 = 0.f, a1 = 0.f;
    #pragma unroll 8
    for (int k = 0; k < DD; ++k) {
        float w = W[k * CC + c];           // coalesced across c
        a0 = fmaf(r0[k], w, a0);
        a1 = fmaf(r1[k], w, a1);
    }

    if (sel == 0) {
        float bb = bxh[c];
        E[(size_t)(row0 + 0) * CC + c] = fexp2(K2 * (a0 + bb));
        E[(size_t)(row0 + 1) * CC + c] = fexp2(K2 * (a1 + bb));
    } else {
        float2 v = {fexp2(K2 * a0), fexp2(K2 * a1)};
        *reinterpret_cast<float2*>(&F[((size_t)b * CC + c) * SL + i0]) = v;
    }
}

// Kernel 2: one block per (b, 4 rows of i). 512 blocks x 1024 threads
// = 2 blocks/CU = 32 waves/CU = 8 waves/SIMD (round 9 ran 4/SIMD; same
// per-element pipe work, double the latency-hiding).
// Phase B: jt = tid&255 -> j pair (float2 F loads); cq = tid>>8 -> 32-c
// quarter. Rational pairing: wa0/u0 + wa1/u1 = (wa0*u1+wa1*u0)/(u0*u1),
// one v_rcp per two c-terms. c-quarter partials merge through a 32 KB LDS
// pool (stride 9 -> conflict-free) that phase D later reuses for partials.
// Softmax max-pass dropped (scores bounded, sum >= 1 -> +eps matches
// reference to <= 1e-7 relative).
__global__ __launch_bounds__(1024, 8) void attn_kernel(
    const float* __restrict__ inps, const float* __restrict__ wei_a,
    const float* __restrict__ E, const float* __restrict__ F,
    float* __restrict__ out)
{
    __shared__ float4 upk[CC];             // E quads {E[i0..i0+3, c]}  (2 KB)
    __shared__ float pool[4 * 16 * DD];    // 32 KB: c-merge (B/C), then phase-D partials
    __shared__ float scT[SL * 4];          // a[i][j] stored [j][4]      (8 KB)
    __shared__ float redw[4 * 4];          // 4 rows x 4 lower-quarter waves

    const int blk = blockIdx.x;            // 512 blocks
    const int b   = blk >> 7;
    const int i0  = (blk & 127) * 4;
    const int bi0 = b * SL + i0;
    const int tid = threadIdx.x;
    const int jt  = tid & 255;             // j-pair index
    const int cq  = tid >> 8;              // c-quarter (wave-uniform)
    const int j0  = jt * 2;

    // Phase A: stage the four block-uniform E rows as quads (128 threads)
    if (tid < CC) {
        float4 u;
        u.x = E[(size_t)(bi0 + 0) * CC + tid];
        u.y = E[(size_t)(bi0 + 1) * CC + tid];
        u.z = E[(size_t)(bi0 + 2) * CC + tid];
        u.w = E[(size_t)(bi0 + 3) * CC + tid];
        upk[tid] = u;
    }
    __syncthreads();                       // barrier 1

    // Phase B: partial s over this thread's 32-c quarter, 4 i's x 2 j's.
    const int c0 = cq * 32;
    const float* fb = F + ((size_t)b * CC + c0) * SL + j0;
    const float4* up = upk + c0;
    const float* wa = wei_a + c0;          // uniform -> s_load (K$ hot)
    float sx[4] = {0.f, 0.f, 0.f, 0.f};
    float sy[4] = {0.f, 0.f, 0.f, 0.f};
    #pragma unroll 4
    for (int cp = 0; cp < 16; ++cp) {
        float2 f0 = *reinterpret_cast<const float2*>(&fb[(size_t)(2 * cp) * SL]);
        float2 f1 = *reinterpret_cast<const float2*>(&fb[(size_t)(2 * cp + 1) * SL]);
        float4 u0 = up[2 * cp];            // broadcast ds_read_b128
        float4 u1 = up[2 * cp + 1];
        float wa0 = wa[2 * cp], wa1 = wa[2 * cp + 1];
        const float* u0p = reinterpret_cast<const float*>(&u0);
        const float* u1p = reinterpret_cast<const float*>(&u1);
        #pragma unroll
        for (int i = 0; i < 4; ++i) {
            float ax = fmaf(u0p[i], f0.x, 1.0f);
            float bx = fmaf(u1p[i], f1.x, 1.0f);
            float numx = fmaf(wa0, bx, wa1 * ax);
            sx[i] = fmaf(numx, frcp(ax * bx), sx[i]);
            float ay = fmaf(u0p[i], f0.y, 1.0f);
            float by = fmaf(u1p[i], f1.y, 1.0f);
            float numy = fmaf(wa0, by, wa1 * ay);
            sy[i] = fmaf(numy, frcp(ay * by), sy[i]);
        }
    }

    // Merge c-quarters 1..3 through the pool (stride 9: gcd(9,32)=1 -> 2-way
    // max per bank = free per m136). Segment stride 2304 = 256*9.
    if (cq > 0) {
        float* m = &pool[(cq - 1) * 2304 + jt * 9];
        #pragma unroll
        for (int i = 0; i < 4; ++i) { m[i] = sx[i]; m[4 + i] = sy[i]; }
    }
    __syncthreads();                       // barrier 2

    // Phase C (threads of quarter 0, 4 waves): merge + exp + row-sum + norm.
    if (cq == 0) {
        #pragma unroll
        for (int seg = 0; seg < 3; ++seg) {
            const float* m = &pool[seg * 2304 + jt * 9];
            #pragma unroll
            for (int i = 0; i < 4; ++i) { sx[i] += m[i]; sy[i] += m[4 + i]; }
        }
        const float KE = -2.8853900817779268f;  // -2*log2(e)
        float ex[4], ey[4];
        const int lane = tid & 63, wv = tid >> 6;   // wv in 0..3
        #pragma unroll
        for (int i = 0; i < 4; ++i) {
            ex[i] = fexp2(sx[i] * KE);
            ey[i] = fexp2(sy[i] * KE);
            float t = ex[i] + ey[i];
            #pragma unroll
            for (int off = 32; off > 0; off >>= 1)
                t += __shfl_xor(t, off, 64);
            if (lane == 0) redw[i * 4 + wv] = t;
        }
        __syncthreads();                   // barrier 3
        float4 av0, av1;
        {
            float S0 = redw[0] + redw[1] + redw[2] + redw[3];
            float S1 = redw[4] + redw[5] + redw[6] + redw[7];
            float S2 = redw[8] + redw[9] + redw[10] + redw[11];
            float S3 = redw[12] + redw[13] + redw[14] + redw[15];
            float r0 = frcp(S0 + 1e-7f), r1 = frcp(S1 + 1e-7f);
            float r2 = frcp(S2 + 1e-7f), r3 = frcp(S3 + 1e-7f);
            av0 = make_float4(ex[0] * r0, ex[1] * r1, ex[2] * r2, ex[3] * r3);
            av1 = make_float4(ey[0] * r0, ey[1] * r1, ey[2] * r2, ey[3] * r3);
        }
        *reinterpret_cast<float4*>(&scT[j0 * 4])     = av0;  // a[*][j0]
        *reinterpret_cast<float4*>(&scT[j0 * 4 + 4]) = av1;  // a[*][j0+1]
    } else {
        __syncthreads();                   // barrier 3 (match)
    }
    __syncthreads();                       // barrier 4: scT ready, pool free

    // Phase D (tid < 512, round-9 shape — each inps float4 feeds 4 rows;
    // upper 8 waves wait at the barrier, consuming no issue slots).
    if (tid < 512) {
        const int dq = (tid & 31) * 4;
        const int jq = tid >> 5;           // 0..15, 32 j each
        const float* ibase = inps + (size_t)b * SL * DD;
        float4 acc0 = {0,0,0,0}, acc1 = {0,0,0,0}, acc2 = {0,0,0,0}, acc3 = {0,0,0,0};
        const int jb = jq * 32;
        #pragma unroll 4
        for (int jj = 0; jj < 32; ++jj) {
            int jx = jb + jj;
            float4 v  = *reinterpret_cast<const float4*>(ibase + (size_t)jx * DD + dq);
            float4 a4 = *reinterpret_cast<const float4*>(&scT[jx * 4]);  // broadcast
            acc0.x = fmaf(a4.x, v.x, acc0.x); acc0.y = fmaf(a4.x, v.y, acc0.y);
            acc0.z = fmaf(a4.x, v.z, acc0.z); acc0.w = fmaf(a4.x, v.w, acc0.w);
            acc1.x = fmaf(a4.y, v.x, acc1.x); acc1.y = fmaf(a4.y, v.y, acc1.y);
            acc1.z = fmaf(a4.y, v.z, acc1.z); acc1.w = fmaf(a4.y, v.w, acc1.w);
            acc2.x = fmaf(a4.z, v.x, acc2.x); acc2.y = fmaf(a4.z, v.y, acc2.y);
            acc2.z = fmaf(a4.z, v.z, acc2.z); acc2.w = fmaf(a4.z, v.w, acc2.w);
            acc3.x = fmaf(a4.w, v.x, acc3.x); acc3.y = fmaf(a4.w, v.y, acc3.y);
            acc3.z = fmaf(a4.w, v.z, acc3.z); acc3.w = fmaf(a4.w, v.w, acc3.w);
        }
        *reinterpret_cast<float4*>(&pool[(0 * 16 + jq) * DD + dq]) = acc0;
        *reinterpret_cast<float4*>(&pool[(1 * 16 + jq) * DD + dq]) = acc1;
        *reinterpret_cast<float4*>(&pool[(2 * 16 + jq) * DD + dq]) = acc2;
        *reinterpret_cast<float4*>(&pool[(3 * 16 + jq) * DD + dq]) = acc3;
    }
    __syncthreads();                       // barrier 5
    if (tid < 512) {
        int i = tid >> 7, d = tid & 127;   // 4 rows x 128 d
        float sum = 0.f;
        #pragma unroll
        for (int q = 0; q < 16; ++q) sum += pool[(i * 16 + q) * DD + d];
        out[(size_t)(bi0 + i) * DD + d] = sum;
    }
}

extern "C" void kernel_launch(void* const* d_in, const int* in_sizes, int n_in,
                              void* d_out, int out_size, void* d_ws, size_t ws_size,
                              hipStream_t stream) {
    const float* inps  = (const float*)d_in[0];  // [B, L, D]
    const float* wei_t = (const float*)d_in[1];  // [D, C]
    const float* wei_x = (const float*)d_in[2];  // [D, C]
    const float* bxh   = (const float*)d_in[3];  // [C]
    const float* wei_a = (const float*)d_in[4];  // [C]
    // d_in[5] = bxa (scalar): uniform shift before softmax -> dropped.
    float* out = (float*)d_out;                  // [B, L, D] fp32

    float* E = (float*)d_ws;                     // [B*L, C]   1 MB
    float* F = E + (size_t)NB * SL * CC;         // [B, C, L]  1 MB

    proj_kernel<<<NB * SL / 2, 256, 0, stream>>>(inps, wei_t, wei_x, bxh, E, F);
    attn_kernel<<<NB * SL / 4, 1024, 0, stream>>>(inps, wei_a, E, F, out);
}